// Round 1
// baseline (695.211 us; speedup 1.0000x reference)
//
#include <hip/hip_runtime.h>
#include <math.h>

#define CCH 32              // channels per row
#define QPR 8               // f4 quads per row (32 ch / 4)
#define CAP 256             // sids owned per block
#define PCH 33              // padded LDS table row stride (uints) — spreads banks
#define ENC_NEGINF 0x007FFFFFu   // enc(-inf)

typedef float f4 __attribute__((ext_vector_type(4)));

// Monotonic bijection float -> uint: a < b  <=>  encf(a) < encf(b) (unsigned).
// atomicMax over encodings == exact float max (no arithmetic, bit-exact).
__device__ __forceinline__ unsigned encf(float x) {
    unsigned b = __float_as_uint(x);
    return (b & 0x80000000u) ? ~b : (b | 0x80000000u);
}
// Decode back to raw float bits; untouched table entries (empty sid) -> +0.0f,
// which implements the reference's isinf -> 0 rule.
__device__ __forceinline__ unsigned decbits(unsigned u) {
    if (u == ENC_NEGINF) return 0u;
    return (u & 0x80000000u) ? (u ^ 0x80000000u) : ~u;
}

// K0: startc[j] = lower_bound(ids, j*CAP) for j in [0, NB].
// 1955 binary searches; replaces the old per-element seg_starts pass.
__global__ void bounds_kernel(const int* __restrict__ ids,
                              int* __restrict__ startc,
                              int N, int NB) {
    int j = blockIdx.x * blockDim.x + threadIdx.x;
    if (j > NB) return;
    int target = j * CAP;
    int lo = 0, hi = N;
    while (lo < hi) {
        int mid = (lo + hi) >> 1;
        if (ids[mid] < target) lo = mid + 1;
        else hi = mid;
    }
    startc[j] = lo;
}

// K1: block b owns sids [b*CAP, (b+1)*CAP) and rows [startc[b], startc[b+1]).
// Every feat byte is read exactly once, fully coalesced (1 KB per wave-instr:
// 8 consecutive rows x 8 quads x 16 B). Reduction in a padded LDS table via
// atomicMax on encoded uints; every output written exactly once, no global
// atomics, no init pass, no decode pass.
__global__ __launch_bounds__(256) void pool_kernel(
    const f4* __restrict__ feat, const int* __restrict__ ids,
    const int* __restrict__ startc, unsigned* __restrict__ out,
    int M) {
    __shared__ unsigned tab[CAP * PCH];
    const int b    = blockIdx.x;
    const int sid0 = b * CAP;
    const int rs   = startc[b];
    const int re   = startc[b + 1];
    const int tid  = threadIdx.x;
    const int q    = tid & (QPR - 1);   // quad within row
    const int rofs = tid >> 3;          // row slot (0..31); wave = 8 consec rows

    for (int e = tid; e < CAP * PCH; e += 256) tab[e] = ENC_NEGINF;
    __syncthreads();

    const int c0 = q * 4;
    int r = rs + rofs;
    // 2-wide manual unroll: two independent 16B loads in flight before the
    // LDS atomics; ids[r] - sid0 is guaranteed in [0, CAP) by construction.
    for (; r + 32 < re; r += 64) {
        f4 v0 = feat[(size_t)r * QPR + q];
        int i0 = ids[r] - sid0;
        f4 v1 = feat[(size_t)(r + 32) * QPR + q];
        int i1 = ids[r + 32] - sid0;
        unsigned* t0 = tab + i0 * PCH + c0;
        atomicMax(t0 + 0, encf(v0.x));
        atomicMax(t0 + 1, encf(v0.y));
        atomicMax(t0 + 2, encf(v0.z));
        atomicMax(t0 + 3, encf(v0.w));
        unsigned* t1 = tab + i1 * PCH + c0;
        atomicMax(t1 + 0, encf(v1.x));
        atomicMax(t1 + 1, encf(v1.y));
        atomicMax(t1 + 2, encf(v1.z));
        atomicMax(t1 + 3, encf(v1.w));
    }
    if (r < re) {   // at most one leftover row per thread
        f4 v = feat[(size_t)r * QPR + q];
        int i0 = ids[r] - sid0;
        unsigned* t0 = tab + i0 * PCH + c0;
        atomicMax(t0 + 0, encf(v.x));
        atomicMax(t0 + 1, encf(v.y));
        atomicMax(t0 + 2, encf(v.z));
        atomicMax(t0 + 3, encf(v.w));
    }
    __syncthreads();

    // Flush: each of this block's sids written exactly once (zeros for empty).
    int nsid = M - sid0; if (nsid > CAP) nsid = CAP;
    unsigned* ob = out + (size_t)sid0 * CCH;
    for (int e = tid; e < nsid * CCH; e += 256) {
        unsigned u = tab[(e >> 5) * PCH + (e & 31)];
        ob[e] = decbits(u);
    }
}

extern "C" void kernel_launch(void* const* d_in, const int* in_sizes, int n_in,
                              void* d_out, int out_size, void* d_ws, size_t ws_size,
                              hipStream_t stream) {
    const f4*  feat = (const f4*)d_in[0];
    const int* ids  = (const int*)d_in[1];

    const int N  = in_sizes[0] / CCH;        // 4,000,000
    const int M  = out_size / CCH;           // 500,000
    const int NB = (M + CAP - 1) / CAP;      // 1954 blocks

    int* startc = (int*)d_ws;                // (NB+1) ints

    int gridA = (NB + 1 + 255) / 256;
    bounds_kernel<<<gridA, 256, 0, stream>>>(ids, startc, N, NB);
    pool_kernel<<<NB, 256, 0, stream>>>(feat, ids, startc,
                                        (unsigned*)d_out, M);
}